// Round 8
// baseline (290.182 us; speedup 1.0000x reference)
//
#include <hip/hip_runtime.h>
#include <hip/hip_bf16.h>
#include <math.h>

// SharedLora on MI355X — round 8.
// r7 kept minimal traffic (335R/81W MB) but stalled on in-loop comp/g2 L1
// loads + low residency. r8: block=640 (10 waves), wave owns 2 clusters,
// lane owns one 4-bin group; comp (2 cols, 40 f32) hoisted into registers
// ONCE per thread; PA inner loop = ds_read_b128 + 8 FMA per a. LDS 21.3 KB,
// __launch_bounds__(640,5) targets VGPR<=102 (2 blocks = 20 waves/CU).
// KL: PQ single pass (480 L2-hot column-quads vs g2 via s_load), L0-2 in
// k_klc. w stored bf16.

#define NROI 256
#define NC 20
#define NFINAL 8000
#define NCUTS 500000
#define TBINS 256
#define NTILE 32           // ceil(8000/256) = 31.25 -> tile 31 has 64 bins

__global__ void k_init(const float* __restrict__ comp,
                       float* __restrict__ g2, float* __restrict__ kl)
{
    const int tid = threadIdx.x;
    if (tid == 0) kl[0] = (float)(-80076800.0 * 1.3244036413128371);
    for (int i = tid; i < 400; i += 256) {
        const int a = i / 20, b = i % 20;
        float s = 0.f;
#pragma unroll
        for (int c = 0; c < 20; c++) s += comp[a * 20 + c] * comp[b * 20 + c];
        // upper-triangular, off-diagonal doubled: q = sum_a x_a * sum_{b>=a} g2 x_b
        g2[i] = (b < a) ? 0.f : (b == a ? s : 2.f * s);
    }
}

__global__ __launch_bounds__(640, 5) void k_main(
    const float* __restrict__ comp, const float* __restrict__ g2,
    const float* __restrict__ wb0, const float* __restrict__ wd0,
    const float* __restrict__ wb1, const float* __restrict__ wd1,
    const float* __restrict__ wb2, const float* __restrict__ wd2,
    const float* __restrict__ wb3, const float* __restrict__ wd3,
    const float* __restrict__ wb4, const float* __restrict__ wd4,
    const float* __restrict__ wb5, const float* __restrict__ wd5,
    const float* __restrict__ wb6, const float* __restrict__ wd6,
    const int* __restrict__ regions_oi,
    __hip_bfloat16* __restrict__ w2,
    float* __restrict__ s_part, float* __restrict__ kl_out)
{
    __shared__ float U_sh[20 * TBINS];   // 20 KiB
    __shared__ float bias_sh[TBINS];     // 1 KiB
    __shared__ float klp[10];

    const int tid = threadIdx.x;
    const int r = blockIdx.x >> 5;
    const int tile = blockIdx.x & 31;
    const int base = tile << 8;
    const int r0 = regions_oi[r];

    const float* __restrict__ p6 = wd6 + (size_t)r0 * (20 * 8000);
    const float* __restrict__ p5 = wd5 + (size_t)r0 * (20 * 4000);
    const float* __restrict__ p4 = wd4 + (size_t)r0 * (20 * 2000);
    const float* __restrict__ p3 = wd3 + (size_t)r0 * (20 * 1000);
    const float* __restrict__ p2 = wd2 + (size_t)r0 * (20 * 400);
    const float* __restrict__ p1 = wd1 + (size_t)r0 * (20 * 200);
    const float* __restrict__ p0 = wd0 + (size_t)r0 * (20 * 40);
    const float* __restrict__ b6 = wb6 + (size_t)r0 * 8000;
    const float* __restrict__ b5 = wb5 + (size_t)r0 * 4000;
    const float* __restrict__ b4 = wb4 + (size_t)r0 * 2000;
    const float* __restrict__ b3 = wb3 + (size_t)r0 * 1000;
    const float* __restrict__ b2 = wb2 + (size_t)r0 * 400;
    const float* __restrict__ b1 = wb1 + (size_t)r0 * 200;
    const float* __restrict__ b0 = wb0 + (size_t)r0 * 40;

    // ---- per-thread comp columns (2 clusters per wave), loaded ONCE ----
    const int wv = tid >> 6, lane = tid & 63;
    const int c0 = wv << 1;
    float f0[20], f1[20];
#pragma unroll
    for (int a = 0; a < 20; a++) {
        const float2 f = *(const float2*)(comp + a * 20 + c0);
        f0[a] = f.x; f1[a] = f.y;
    }

    // ---- P0: stage U (1280 float4 units) + bias (64 units) ----
#pragma unroll 1
    for (int it = 0; it < 3; it++) {
        const int u = it * 640 + tid;
        if (u >= 1344) break;
        if (u < 1280) {
            const int a = u >> 6, jq = u & 63;
            const int j = base + 4 * jq;
            float4 uu;
            if (j < NFINAL) {
                const float4 v6 = *(const float4*)(p6 + (size_t)a * 8000 + j);
                const float2 v5 = *(const float2*)(p5 + a * 4000 + (j >> 1));
                const float sc = p4[a * 2000 + (j >> 2)] + p3[a * 1000 + (j >> 3)]
                               + p2[a * 400 + j / 20] + p1[a * 200 + j / 40]
                               + p0[a * 40 + j / 200];
                const float c01 = sc + v5.x, c23 = sc + v5.y;
                uu.x = v6.x + c01; uu.y = v6.y + c01;
                uu.z = v6.z + c23; uu.w = v6.w + c23;
            } else {
                uu.x = uu.y = uu.z = uu.w = 0.f;
            }
            *(float4*)(&U_sh[a * TBINS + 4 * jq]) = uu;
        } else {
            const int jq = u - 1280;
            const int j = base + 4 * jq;
            float4 uu;
            if (j < NFINAL) {
                const float4 v6 = *(const float4*)(b6 + j);
                const float2 v5 = *(const float2*)(b5 + (j >> 1));
                const float sc = b4[j >> 2] + b3[j >> 3] + b2[j / 20]
                               + b1[j / 40] + b0[j / 200];
                const float c01 = sc + v5.x, c23 = sc + v5.y;
                uu.x = v6.x + c01; uu.y = v6.y + c01;
                uu.z = v6.z + c23; uu.w = v6.w + c23;
            } else {
                uu.x = uu.y = uu.z = uu.w = -1e30f;
            }
            *(float4*)(&bias_sh[4 * jq]) = uu;
        }
    }
    __syncthreads();

    // ---- PA: lane = one 4-bin group, wave = clusters {c0, c0+1} ----
    float sexp0 = 0.f, sexp1 = 0.f;
    const int j = base + 4 * lane;
    if (j < NFINAL) {
        float4 acc0 = *(const float4*)(&bias_sh[4 * lane]);
        float4 acc1 = acc0;
#pragma unroll
        for (int a = 0; a < 20; a++) {
            const float4 u = *(const float4*)(&U_sh[a * TBINS + 4 * lane]);
            const float g0 = f0[a], g1 = f1[a];
            acc0.x += g0 * u.x; acc0.y += g0 * u.y;
            acc0.z += g0 * u.z; acc0.w += g0 * u.w;
            acc1.x += g1 * u.x; acc1.y += g1 * u.y;
            acc1.z += g1 * u.z; acc1.w += g1 * u.w;
        }
        union { __hip_bfloat162 h2[2]; uint2 u2; } pk;
        pk.h2[0] = __float22bfloat162_rn(make_float2(acc0.x, acc0.y));
        pk.h2[1] = __float22bfloat162_rn(make_float2(acc0.z, acc0.w));
        *(uint2*)(w2 + (size_t)(r * 20 + c0) * 8000 + j) = pk.u2;
        pk.h2[0] = __float22bfloat162_rn(make_float2(acc1.x, acc1.y));
        pk.h2[1] = __float22bfloat162_rn(make_float2(acc1.z, acc1.w));
        *(uint2*)(w2 + (size_t)(r * 20 + c0 + 1) * 8000 + j) = pk.u2;
        // |w| small (~<4): unnormalized exp-sum safe in f32
        sexp0 = __expf(acc0.x) + __expf(acc0.y) + __expf(acc0.z) + __expf(acc0.w);
        sexp1 = __expf(acc1.x) + __expf(acc1.y) + __expf(acc1.z) + __expf(acc1.w);
    }
#pragma unroll
    for (int off = 32; off > 0; off >>= 1) {
        sexp0 += __shfl_down(sexp0, off, 64);
        sexp1 += __shfl_down(sexp1, off, 64);
    }
    if (lane == 0) {
        s_part[(size_t)blockIdx.x * 20 + c0]     = sexp0;
        s_part[(size_t)blockIdx.x * 20 + c0 + 1] = sexp1;
    }

    // ---- PQ: KL quads for this tile's L6/L5/L4/L3 columns (L2-hot) ----
    float q = 0.f;
    if (tid < 480) {
        const float* P; int K, col;
        if (tid < 256)      { P = p6; K = 8000; col = base + tid; }
        else if (tid < 384) { P = p5; K = 4000; col = (base >> 1) + tid - 256; }
        else if (tid < 448) { P = p4; K = 2000; col = (base >> 2) + tid - 384; }
        else                { P = p3; K = 1000; col = (base >> 3) + tid - 448; }
        if (col < K) {
            float x[20];
#pragma unroll
            for (int a = 0; a < 20; a++) x[a] = P[(size_t)a * K + col];
#pragma unroll
            for (int a = 0; a < 20; a++) {
                float t = g2[a * 20 + a] * x[a];
#pragma unroll
                for (int b = a + 1; b < 20; b++) t += g2[a * 20 + b] * x[b];
                q += x[a] * t;
            }
        }
    }
#pragma unroll
    for (int off = 32; off > 0; off >>= 1) q += __shfl_down(q, off, 64);
    if (lane == 0) klp[wv] = q;
    __syncthreads();
    if (tid == 0) {
        float s = 0.f;
#pragma unroll
        for (int k = 0; k < 10; k++) s += klp[k];
        atomicAdd(kl_out, s * (-0.5f / 2.25f));
    }
}

// KL quads for levels 0..2 (40+200+400 = 640 cols per region)
__global__ __launch_bounds__(256, 2) void k_klc(
    const float* __restrict__ g2,
    const float* __restrict__ wd0, const float* __restrict__ wd1,
    const float* __restrict__ wd2,
    const int* __restrict__ regions_oi, float* __restrict__ kl_out)
{
    __shared__ float klp[4];
    const int tid = threadIdx.x;
    const int r0 = regions_oi[blockIdx.x];
    const float* __restrict__ p2 = wd2 + (size_t)r0 * (20 * 400);
    const float* __restrict__ p1 = wd1 + (size_t)r0 * (20 * 200);
    const float* __restrict__ p0 = wd0 + (size_t)r0 * (20 * 40);

    float q = 0.f;
#pragma unroll 1
    for (int it = 0; it < 3; it++) {
        const int u = it * 256 + tid;
        if (u >= 640) break;
        const float* P; int K, col;
        if (u < 400)      { P = p2; K = 400; col = u; }
        else if (u < 600) { P = p1; K = 200; col = u - 400; }
        else              { P = p0; K = 40;  col = u - 600; }
        float x[20];
#pragma unroll
        for (int a = 0; a < 20; a++) x[a] = P[a * K + col];
#pragma unroll
        for (int a = 0; a < 20; a++) {
            float t = g2[a * 20 + a] * x[a];
#pragma unroll
            for (int b = a + 1; b < 20; b++) t += g2[a * 20 + b] * x[b];
            q += x[a] * t;
        }
    }
#pragma unroll
    for (int off = 32; off > 0; off >>= 1) q += __shfl_down(q, off, 64);
    if ((tid & 63) == 0) klp[tid >> 6] = q;
    __syncthreads();
    if (tid == 0)
        atomicAdd(kl_out, (klp[0] + klp[1] + klp[2] + klp[3]) * (-0.5f / 2.25f));
}

__global__ void k_sub(const float* __restrict__ s_part, float* __restrict__ sub)
{
    const int i = blockIdx.x * 256 + threadIdx.x;
    if (i >= NROI * NC) return;
    const int r = i / 20, c = i % 20;
    float s = 0.f;
#pragma unroll 1
    for (int t = 0; t < NTILE; t++) s += s_part[(size_t)(r * NTILE + t) * 20 + c];
    sub[i] = logf(s) + 3.2188758248682006f;   // + log(25)
}

__global__ void k_gather(const int* __restrict__ lri, const int* __restrict__ lci,
                         const int* __restrict__ cli, const int* __restrict__ coords,
                         const __hip_bfloat16* __restrict__ w2,
                         const float* __restrict__ sub,
                         float* __restrict__ out)
{
    const int i = blockIdx.x * 256 + threadIdx.x;
    if (i >= NCUTS) return;
    const int r = lri[i];
    const int c = cli[lci[i]];
    int co = coords[i];
    co = co < 0 ? 0 : (co > 199999 ? 199999 : co);
    const int bin = co / 25;
    const int rc = r * 20 + c;
    out[i] = __bfloat162float(w2[(size_t)rc * 8000 + bin]) - sub[rc];
}

extern "C" void kernel_launch(void* const* d_in, const int* in_sizes, int n_in,
                              void* d_out, int out_size, void* d_ws, size_t ws_size,
                              hipStream_t stream)
{
    const float* comp = (const float*)d_in[0];
    const float* wb[7];
    const float* wd[7];
    if (in_sizes[2] == 400000) {
        for (int l = 0; l < 7; l++) { wb[l] = (const float*)d_in[1 + 2 * l]; wd[l] = (const float*)d_in[2 + 2 * l]; }
    } else {
        for (int l = 0; l < 7; l++) { wb[l] = (const float*)d_in[1 + l]; wd[l] = (const float*)d_in[8 + l]; }
    }
    const int* regions_oi = (const int*)d_in[15];
    const int* lri   = (const int*)d_in[16];
    const int* lci   = (const int*)d_in[17];
    const int* cli   = (const int*)d_in[18];
    const int* coords= (const int*)d_in[19];
    float* out = (float*)d_out;

    __hip_bfloat16* w2 = (__hip_bfloat16*)d_ws;                     // 81.92 MB
    float* s_part = (float*)(w2 + (size_t)NROI * NC * NFINAL);      // 8192*20 f32
    float* sub    = s_part + (size_t)NROI * NTILE * 20;             // 5120 f32
    float* g2buf  = sub + NROI * NC;                                // 400 f32
    const size_t need = (size_t)NROI * NC * NFINAL * 2
                      + ((size_t)NROI * NTILE * 20 + NROI * NC + 400) * sizeof(float);
    if (ws_size < need) return;

    k_init<<<1, 256, 0, stream>>>(comp, g2buf, out + NCUTS);
    k_main<<<NROI * NTILE, 640, 0, stream>>>(comp, g2buf,
        wb[0], wd[0], wb[1], wd[1], wb[2], wd[2], wb[3], wd[3],
        wb[4], wd[4], wb[5], wd[5], wb[6], wd[6],
        regions_oi, w2, s_part, out + NCUTS);
    k_klc<<<NROI, 256, 0, stream>>>(g2buf, wd[0], wd[1], wd[2],
        regions_oi, out + NCUTS);
    k_sub<<<(NROI * NC + 255) / 256, 256, 0, stream>>>(s_part, sub);
    k_gather<<<(NCUTS + 255) / 256, 256, 0, stream>>>(lri, lci, cli, coords,
        w2, sub, out);
}